// Round 7
// baseline (247.319 us; speedup 1.0000x reference)
//
#include <hip/hip_runtime.h>

#define N_NODES 16384
#define FIN     256
#define FOUT    64
#define MAXW    128   // nnz/row: mean ~33, sigma ~5.7; R5 passed with 128 (~16 sigma)
#define MAXWF   512   // fallback path cap

typedef float f32x4 __attribute__((ext_vector_type(4)));

// ---------------- Kernel 1: support = x @ weight  [N,FIN]@[FIN,FOUT] ----------
__global__ __launch_bounds__(256) void support_gemm(
    const float* __restrict__ x, const float* __restrict__ w,
    float* __restrict__ support) {
  __shared__ float wl[FIN * FOUT];   // 64 KB  [k][c]
  __shared__ float xl[16][FIN];      // 16 KB  [r][k]
  const int t = threadIdx.x;

  const float4* w4 = (const float4*)w;
  float4* wl4 = (float4*)wl;
#pragma unroll
  for (int i = 0; i < 16; ++i) wl4[i * 256 + t] = w4[i * 256 + t];

  const int row0 = blockIdx.x * 16;
  const float4* x4 = (const float4*)(x + (size_t)row0 * FIN);
  float4* xl4 = (float4*)xl;
#pragma unroll
  for (int i = 0; i < 4; ++i) xl4[i * 256 + t] = x4[i * 256 + t];
  __syncthreads();

  const int wv = t >> 6, c = t & 63, r0 = wv * 4;
  float acc0 = 0.f, acc1 = 0.f, acc2 = 0.f, acc3 = 0.f;
#pragma unroll 4
  for (int k = 0; k < FIN; k += 4) {
    const f32x4 xv0 = *(const f32x4*)&xl[r0 + 0][k];
    const f32x4 xv1 = *(const f32x4*)&xl[r0 + 1][k];
    const f32x4 xv2 = *(const f32x4*)&xl[r0 + 2][k];
    const f32x4 xv3 = *(const f32x4*)&xl[r0 + 3][k];
    const float w0 = wl[(k + 0) * FOUT + c];
    const float w1 = wl[(k + 1) * FOUT + c];
    const float w2 = wl[(k + 2) * FOUT + c];
    const float w3 = wl[(k + 3) * FOUT + c];
    acc0 += xv0[0] * w0 + xv0[1] * w1 + xv0[2] * w2 + xv0[3] * w3;
    acc1 += xv1[0] * w0 + xv1[1] * w1 + xv1[2] * w2 + xv1[3] * w3;
    acc2 += xv2[0] * w0 + xv2[1] * w1 + xv2[2] * w2 + xv2[3] * w3;
    acc3 += xv3[0] * w0 + xv3[1] * w1 + xv3[2] * w2 + xv3[3] * w3;
  }
  float* outp = support + (size_t)(row0 + r0) * FOUT + c;
  outp[0 * FOUT] = acc0; outp[1 * FOUT] = acc1;
  outp[2 * FOUT] = acc2; outp[3 * FOUT] = acc3;
}

// ---------------- Kernel 2: adj scan via global_load_lds DMA ------------------
// Wave-per-row, wave-private double-buffered LDS chunks (4 KB each), counted
// vmcnt waits (never drain mid-loop), NO __syncthreads. Compaction = proven
// R4 LDS atomics. Writes per-row neighbor list + count to ws.
__global__ __launch_bounds__(256) void scan_dma(
    const float* __restrict__ adj, int* __restrict__ nbrlist,
    int* __restrict__ nbrcnt) {
  __shared__ float buf[4][2][1024];   // 32 KB: per-wave 2 x 4 KB chunks
  __shared__ int   nbr[4][MAXW];      // 2 KB
  __shared__ int   cnt[4];

  const int t = threadIdx.x, wv = t >> 6, lane = t & 63;
  const int row = blockIdx.x * 4 + wv;
  if (lane == 0) cnt[wv] = 0;   // wave-lockstep: ordered before this wave's atomics

  const char* rowp = (const char*)(adj + (size_t)row * N_NODES);

  // prologue: DMA chunks 0 and 1 (4 x 1KB instructions each; LDS dest is
  // wave-uniform base + lane*16, global src is per-lane contiguous)
#pragma unroll
  for (int c0 = 0; c0 < 2; ++c0) {
    char* lb = (char*)&buf[wv][c0][0];
    const char* gp = rowp + c0 * 4096 + lane * 16;
#pragma unroll
    for (int i = 0; i < 4; ++i)
      __builtin_amdgcn_global_load_lds((const void*)(gp + i * 1024),
                                       (void*)(lb + i * 1024), 16, 0, 0);
  }

#pragma unroll 1
  for (int c = 0; c < 16; ++c) {
    // wait for chunk c's 4 loads; chunk c+1's 4 may stay in flight
    if (c < 15) asm volatile("s_waitcnt vmcnt(4)" ::: "memory");
    else        asm volatile("s_waitcnt vmcnt(0)" ::: "memory");
    __builtin_amdgcn_sched_barrier(0);

    const f32x4* p = (const f32x4*)&buf[wv][c & 1][0];
#pragma unroll
    for (int j = 0; j < 4; ++j) {
      const f32x4 a = p[j * 64 + lane];
      const int nz = (a[0] != 0.f) + (a[1] != 0.f) + (a[2] != 0.f) + (a[3] != 0.f);
      if (nz) {
        int pp = atomicAdd(&cnt[wv], nz);
        if (pp + nz <= MAXW) {
          const int kb = c * 1024 + (j * 64 + lane) * 4;
          if (a[0] != 0.f) nbr[wv][pp++] = kb;
          if (a[1] != 0.f) nbr[wv][pp++] = kb + 1;
          if (a[2] != 0.f) nbr[wv][pp++] = kb + 2;
          if (a[3] != 0.f) nbr[wv][pp++] = kb + 3;
        }
      }
    }
    // all ds_reads of this chunk consumed; safe to overwrite its buffer
    asm volatile("s_waitcnt lgkmcnt(0)" ::: "memory");
    __builtin_amdgcn_sched_barrier(0);
    if (c + 2 < 16) {
      char* lb = (char*)&buf[wv][c & 1][0];
      const char* gp = rowp + (c + 2) * 4096 + lane * 16;
#pragma unroll
      for (int i = 0; i < 4; ++i)
        __builtin_amdgcn_global_load_lds((const void*)(gp + i * 1024),
                                         (void*)(lb + i * 1024), 16, 0, 0);
    }
  }

  // write compacted list + count (wave-private, tiny)
  const int m = min(cnt[wv], MAXW);
  int* rowlist = nbrlist + (size_t)row * MAXW;
  for (int i = lane; i < m; i += 64) rowlist[i] = nbr[wv][i];
  if (lane == 0) nbrcnt[row] = m;
}

// ---------------- Kernel 3: gather + mean + bias (proven R5) ------------------
__global__ __launch_bounds__(256) void gather_mean(
    const int* __restrict__ nbrlist, const int* __restrict__ nbrcnt,
    const float* __restrict__ support, const float* __restrict__ bias,
    float* __restrict__ out) {
  const int t = threadIdx.x, wv = t >> 6, lane = t & 63;
  const int row = blockIdx.x * 4 + wv;

  const int m = nbrcnt[row];
  const int* rowlist = nbrlist + (size_t)row * MAXW;
  const float* sup = support + lane;

  float s0 = 0.f, s1 = 0.f, s2 = 0.f, s3 = 0.f;
  int   c0 = 0, c1 = 0, c2 = 0, c3 = 0;
  int n = 0;
  for (; n + 4 <= m; n += 4) {
    const float v0 = sup[(size_t)rowlist[n + 0] * FOUT];
    const float v1 = sup[(size_t)rowlist[n + 1] * FOUT];
    const float v2 = sup[(size_t)rowlist[n + 2] * FOUT];
    const float v3 = sup[(size_t)rowlist[n + 3] * FOUT];
    s0 += v0; c0 += (v0 != 0.f);
    s1 += v1; c1 += (v1 != 0.f);
    s2 += v2; c2 += (v2 != 0.f);
    s3 += v3; c3 += (v3 != 0.f);
  }
  for (; n < m; ++n) {
    const float v = sup[(size_t)rowlist[n] * FOUT];
    s0 += v; c0 += (v != 0.f);
  }
  const float s = (s0 + s1) + (s2 + s3);
  const int   c = (c0 + c1) + (c2 + c3);
  out[(size_t)row * FOUT + lane] = s / (float)c + bias[lane];
}

// ---------------- Fallback (R4-proven fused aggregate) ------------------------
__global__ __launch_bounds__(256) void aggregate_fused(
    const float* __restrict__ adj, const float* __restrict__ support,
    const float* __restrict__ bias, float* __restrict__ out) {
  __shared__ int nbr[4][MAXWF];
  __shared__ int cnt[4];
  const int t = threadIdx.x, wv = t >> 6, lane = t & 63;
  const int row = blockIdx.x * 4 + wv;
  if (lane == 0) cnt[wv] = 0;
  const f32x4* a4 = (const f32x4*)(adj + (size_t)row * N_NODES);
#pragma unroll 1
  for (int h = 0; h < 8; ++h) {
    f32x4 av[8];
#pragma unroll
    for (int j = 0; j < 8; ++j)
      av[j] = __builtin_nontemporal_load(&a4[h * 512 + j * 64 + lane]);
#pragma unroll
    for (int j = 0; j < 8; ++j) {
      const f32x4 a = av[j];
      const int nz = (a[0] != 0.f) + (a[1] != 0.f) + (a[2] != 0.f) + (a[3] != 0.f);
      if (nz) {
        int p = atomicAdd(&cnt[wv], nz);
        if (p + nz <= MAXWF) {
          const int kb = (h * 512 + j * 64 + lane) * 4;
          if (a[0] != 0.f) nbr[wv][p++] = kb;
          if (a[1] != 0.f) nbr[wv][p++] = kb + 1;
          if (a[2] != 0.f) nbr[wv][p++] = kb + 2;
          if (a[3] != 0.f) nbr[wv][p++] = kb + 3;
        }
      }
    }
  }
  const int m = min(cnt[wv], MAXWF);
  float s0 = 0.f, s1 = 0.f, s2 = 0.f, s3 = 0.f;
  int   c0 = 0, c1 = 0, c2 = 0, c3 = 0;
  const float* sup = support + lane;
  int n = 0;
  for (; n + 4 <= m; n += 4) {
    const float v0 = sup[(size_t)nbr[wv][n + 0] * FOUT];
    const float v1 = sup[(size_t)nbr[wv][n + 1] * FOUT];
    const float v2 = sup[(size_t)nbr[wv][n + 2] * FOUT];
    const float v3 = sup[(size_t)nbr[wv][n + 3] * FOUT];
    s0 += v0; c0 += (v0 != 0.f);
    s1 += v1; c1 += (v1 != 0.f);
    s2 += v2; c2 += (v2 != 0.f);
    s3 += v3; c3 += (v3 != 0.f);
  }
  for (; n < m; ++n) {
    const float v = sup[(size_t)nbr[wv][n] * FOUT];
    s0 += v; c0 += (v != 0.f);
  }
  const float s = (s0 + s1) + (s2 + s3);
  const int cc = (c0 + c1) + (c2 + c3);
  out[(size_t)row * FOUT + lane] = s / (float)cc + bias[lane];
}

extern "C" void kernel_launch(void* const* d_in, const int* in_sizes, int n_in,
                              void* d_out, int out_size, void* d_ws, size_t ws_size,
                              hipStream_t stream) {
  const float* x    = (const float*)d_in[0];
  const float* adj  = (const float*)d_in[1];
  const float* w    = (const float*)d_in[2];
  const float* bias = (const float*)d_in[3];
  float* out = (float*)d_out;

  const size_t sup_bytes  = (size_t)N_NODES * FOUT * 4;   // 4 MB
  const size_t list_bytes = (size_t)N_NODES * MAXW * 4;   // 8 MB
  const size_t cnt_bytes  = (size_t)N_NODES * 4;          // 64 KB
  float* support = (float*)d_ws;

  support_gemm<<<N_NODES / 16, 256, 0, stream>>>(x, w, support);

  if (ws_size >= sup_bytes + list_bytes + cnt_bytes) {
    int* nbrlist = (int*)((char*)d_ws + sup_bytes);
    int* nbrcnt  = (int*)((char*)d_ws + sup_bytes + list_bytes);
    scan_dma<<<N_NODES / 4, 256, 0, stream>>>(adj, nbrlist, nbrcnt);
    gather_mean<<<N_NODES / 4, 256, 0, stream>>>(nbrlist, nbrcnt, support, bias, out);
  } else {
    aggregate_fused<<<N_NODES / 4, 256, 0, stream>>>(adj, support, bias, out);
  }
}

// Round 8
// 223.475 us; speedup vs baseline: 1.1067x; 1.1067x over previous
//
#include <hip/hip_runtime.h>

#define N_NODES 16384
#define FIN     256
#define FOUT    64
#define MAXW    512    // neighbor cap per row: mean ~32, sigma ~5.7 -> 84 sigma

typedef float f32x4 __attribute__((ext_vector_type(4)));

// ---------------- Kernel 1: support = x @ weight  [N,FIN]@[FIN,FOUT] ----------
__global__ __launch_bounds__(256) void support_gemm(
    const float* __restrict__ x, const float* __restrict__ w,
    float* __restrict__ support) {
  __shared__ float wl[FIN * FOUT];   // 64 KB  [k][c]
  __shared__ float xl[16][FIN];      // 16 KB  [r][k]
  const int t = threadIdx.x;

  const float4* w4 = (const float4*)w;
  float4* wl4 = (float4*)wl;
#pragma unroll
  for (int i = 0; i < 16; ++i) wl4[i * 256 + t] = w4[i * 256 + t];

  const int row0 = blockIdx.x * 16;
  const float4* x4 = (const float4*)(x + (size_t)row0 * FIN);
  float4* xl4 = (float4*)xl;
#pragma unroll
  for (int i = 0; i < 4; ++i) xl4[i * 256 + t] = x4[i * 256 + t];
  __syncthreads();

  const int wv = t >> 6;        // wave id 0..3
  const int c  = t & 63;        // output column
  const int r0 = wv * 4;        // this wave's 4 rows
  float acc0 = 0.f, acc1 = 0.f, acc2 = 0.f, acc3 = 0.f;

#pragma unroll 4
  for (int k = 0; k < FIN; k += 4) {
    const f32x4 xv0 = *(const f32x4*)&xl[r0 + 0][k];
    const f32x4 xv1 = *(const f32x4*)&xl[r0 + 1][k];
    const f32x4 xv2 = *(const f32x4*)&xl[r0 + 2][k];
    const f32x4 xv3 = *(const f32x4*)&xl[r0 + 3][k];
    const float w0 = wl[(k + 0) * FOUT + c];
    const float w1 = wl[(k + 1) * FOUT + c];
    const float w2 = wl[(k + 2) * FOUT + c];
    const float w3 = wl[(k + 3) * FOUT + c];
    acc0 += xv0[0] * w0 + xv0[1] * w1 + xv0[2] * w2 + xv0[3] * w3;
    acc1 += xv1[0] * w0 + xv1[1] * w1 + xv1[2] * w2 + xv1[3] * w3;
    acc2 += xv2[0] * w0 + xv2[1] * w1 + xv2[2] * w2 + xv2[3] * w3;
    acc3 += xv3[0] * w0 + xv3[1] * w1 + xv3[2] * w2 + xv3[3] * w3;
  }
  float* outp = support + (size_t)(row0 + r0) * FOUT + c;
  outp[0 * FOUT] = acc0;
  outp[1 * FOUT] = acc1;
  outp[2 * FOUT] = acc2;
  outp[3 * FOUT] = acc3;
}

// ---------------- Kernel 2: sparse mean-aggregate + bias ----------------------
// R3-winning structure (203.4 us), single change: PLAIN cached loads on the
// adj stream instead of nontemporal (A/B of the NT-read-path ceiling theory).
// Wave-per-row, barrier-free: per batch, 8 float4 loads issued back-to-back,
// then LDS-atomic compaction; end-of-row 4-chain gather of support + epilogue.
__global__ __launch_bounds__(256, 6) void aggregate(
    const float* __restrict__ adj, const float* __restrict__ support,
    const float* __restrict__ bias, float* __restrict__ out) {
  __shared__ int nbr[4][MAXW];
  __shared__ int cnt[4];

  const int t    = threadIdx.x;
  const int wv   = t >> 6;
  const int lane = t & 63;
  const int row  = blockIdx.x * 4 + wv;

  if (lane == 0) cnt[wv] = 0;   // wave-lockstep: ordered before this wave's atomics

  const f32x4* a4 = (const f32x4*)(adj + (size_t)row * N_NODES);
#pragma unroll 1
  for (int h = 0; h < 8; ++h) {
    f32x4 av[8];
#pragma unroll
    for (int j = 0; j < 8; ++j)
      av[j] = a4[h * 512 + j * 64 + lane];          // cached (no nt)
#pragma unroll
    for (int j = 0; j < 8; ++j) {
      const f32x4 a = av[j];
      const int nz = (a[0] != 0.f) + (a[1] != 0.f) + (a[2] != 0.f) + (a[3] != 0.f);
      if (nz) {
        int p = atomicAdd(&cnt[wv], nz);
        if (p + nz <= MAXW) {
          const int kbase = (h * 512 + j * 64 + lane) * 4;
          if (a[0] != 0.f) nbr[wv][p++] = kbase;
          if (a[1] != 0.f) nbr[wv][p++] = kbase + 1;
          if (a[2] != 0.f) nbr[wv][p++] = kbase + 2;
          if (a[3] != 0.f) nbr[wv][p++] = kbase + 3;
        }
      }
    }
  }

  // Phase B: gather support rows, 4 independent chains.
  const int m = min(cnt[wv], MAXW);
  const float* sup = support + lane;
  float s0 = 0.f, s1 = 0.f, s2 = 0.f, s3 = 0.f;
  int   c0 = 0, c1 = 0, c2 = 0, c3 = 0;
  int n = 0;
  for (; n + 4 <= m; n += 4) {
    const float v0 = sup[(size_t)nbr[wv][n + 0] * FOUT];
    const float v1 = sup[(size_t)nbr[wv][n + 1] * FOUT];
    const float v2 = sup[(size_t)nbr[wv][n + 2] * FOUT];
    const float v3 = sup[(size_t)nbr[wv][n + 3] * FOUT];
    s0 += v0; c0 += (v0 != 0.f);
    s1 += v1; c1 += (v1 != 0.f);
    s2 += v2; c2 += (v2 != 0.f);
    s3 += v3; c3 += (v3 != 0.f);
  }
  for (; n < m; ++n) {
    const float v = sup[(size_t)nbr[wv][n] * FOUT];
    s0 += v; c0 += (v != 0.f);
  }
  const float s = (s0 + s1) + (s2 + s3);
  const int   c = (c0 + c1) + (c2 + c3);
  out[(size_t)row * FOUT + lane] = s / (float)c + bias[lane];
}

extern "C" void kernel_launch(void* const* d_in, const int* in_sizes, int n_in,
                              void* d_out, int out_size, void* d_ws, size_t ws_size,
                              hipStream_t stream) {
  const float* x    = (const float*)d_in[0];
  const float* adj  = (const float*)d_in[1];
  const float* w    = (const float*)d_in[2];
  const float* bias = (const float*)d_in[3];
  float* out = (float*)d_out;
  float* support = (float*)d_ws;   // 4 MB scratch

  support_gemm<<<N_NODES / 16, 256, 0, stream>>>(x, w, support);
  aggregate<<<N_NODES / 4, 256, 0, stream>>>(adj, support, bias, out);
}

// Round 9
// 192.611 us; speedup vs baseline: 1.2840x; 1.1602x over previous
//
#include <hip/hip_runtime.h>

#define N_NODES 16384
#define FIN     256
#define FOUT    64
#define MAXWPW  128   // per-wave list cap (wave scans 1/4 row: mean ~8, sigma ~2.9)

typedef float f32x4 __attribute__((ext_vector_type(4)));

// ---------------- Kernel 1: support = x @ weight  [N,FIN]@[FIN,FOUT] ----------
__global__ __launch_bounds__(256) void support_gemm(
    const float* __restrict__ x, const float* __restrict__ w,
    float* __restrict__ support) {
  __shared__ float wl[FIN * FOUT];   // 64 KB  [k][c]
  __shared__ float xl[16][FIN];      // 16 KB  [r][k]
  const int t = threadIdx.x;

  const float4* w4 = (const float4*)w;
  float4* wl4 = (float4*)wl;
#pragma unroll
  for (int i = 0; i < 16; ++i) wl4[i * 256 + t] = w4[i * 256 + t];

  const int row0 = blockIdx.x * 16;
  const float4* x4 = (const float4*)(x + (size_t)row0 * FIN);
  float4* xl4 = (float4*)xl;
#pragma unroll
  for (int i = 0; i < 4; ++i) xl4[i * 256 + t] = x4[i * 256 + t];
  __syncthreads();

  const int wv = t >> 6, c = t & 63, r0 = wv * 4;
  float acc0 = 0.f, acc1 = 0.f, acc2 = 0.f, acc3 = 0.f;
#pragma unroll 4
  for (int k = 0; k < FIN; k += 4) {
    const f32x4 xv0 = *(const f32x4*)&xl[r0 + 0][k];
    const f32x4 xv1 = *(const f32x4*)&xl[r0 + 1][k];
    const f32x4 xv2 = *(const f32x4*)&xl[r0 + 2][k];
    const f32x4 xv3 = *(const f32x4*)&xl[r0 + 3][k];
    const float w0 = wl[(k + 0) * FOUT + c];
    const float w1 = wl[(k + 1) * FOUT + c];
    const float w2 = wl[(k + 2) * FOUT + c];
    const float w3 = wl[(k + 3) * FOUT + c];
    acc0 += xv0[0] * w0 + xv0[1] * w1 + xv0[2] * w2 + xv0[3] * w3;
    acc1 += xv1[0] * w0 + xv1[1] * w1 + xv1[2] * w2 + xv1[3] * w3;
    acc2 += xv2[0] * w0 + xv2[1] * w1 + xv2[2] * w2 + xv2[3] * w3;
    acc3 += xv3[0] * w0 + xv3[1] * w1 + xv3[2] * w2 + xv3[3] * w3;
  }
  float* outp = support + (size_t)(row0 + r0) * FOUT + c;
  outp[0 * FOUT] = acc0;
  outp[1 * FOUT] = acc1;
  outp[2 * FOUT] = acc2;
  outp[3 * FOUT] = acc3;
}

// ---------------- Kernel 2: block-per-row cooperative aggregate ---------------
// All 4 waves of a block walk ONE adj row jointly: wave wv takes quads
// j*256 + wv*64 + lane (j=0..15), so the block's instantaneous read window is
// a contiguous 4 KB advancing front. Only 4 blocks/CU resident -> ~1024 active
// DRAM streams chip-wide (vs 6144 in wave-per-row), targeting row-hit regime.
// Per-wave private compaction (no cross-wave atomics); one __syncthreads;
// 4-way LDS reduce + fused mean/bias epilogue.
__global__ __launch_bounds__(256, 4) void aggregate(
    const float* __restrict__ adj, const float* __restrict__ support,
    const float* __restrict__ bias, float* __restrict__ out) {
  __shared__ int   nbr[4][MAXWPW];
  __shared__ int   cnt[4];
  __shared__ float sred[4][FOUT];
  __shared__ int   cred[4][FOUT];

  const int t    = threadIdx.x;
  const int wv   = t >> 6;
  const int lane = t & 63;
  const int row  = blockIdx.x;

  if (lane == 0) cnt[wv] = 0;   // wave-private; ordered before this wave's atomics

  const f32x4* a4 = (const f32x4*)(adj + (size_t)row * N_NODES);

  // two batches of 8 back-to-back nt loads (R2-proven shape), fine-interleaved
#pragma unroll 1
  for (int b = 0; b < 2; ++b) {
    f32x4 A[8];
#pragma unroll
    for (int j = 0; j < 8; ++j)
      A[j] = __builtin_nontemporal_load(&a4[(b * 8 + j) * 256 + wv * 64 + lane]);
#pragma unroll
    for (int j = 0; j < 8; ++j) {
      const f32x4 a = A[j];
      const int nz = (a[0] != 0.f) + (a[1] != 0.f) + (a[2] != 0.f) + (a[3] != 0.f);
      if (nz) {
        int p = atomicAdd(&cnt[wv], nz);
        if (p + nz <= MAXWPW) {
          const int kbase = ((b * 8 + j) * 256 + wv * 64 + lane) * 4;
          if (a[0] != 0.f) nbr[wv][p++] = kbase;
          if (a[1] != 0.f) nbr[wv][p++] = kbase + 1;
          if (a[2] != 0.f) nbr[wv][p++] = kbase + 2;
          if (a[3] != 0.f) nbr[wv][p++] = kbase + 3;
        }
      }
    }
  }

  // per-wave gather of its own finds (support rows are L2/L3-resident)
  const int m = min(cnt[wv], MAXWPW);
  const float* sup = support + lane;
  float s0 = 0.f, s1 = 0.f, s2 = 0.f, s3 = 0.f;
  int   c0 = 0, c1 = 0, c2 = 0, c3 = 0;
  int n = 0;
  for (; n + 4 <= m; n += 4) {
    const float v0 = sup[(size_t)nbr[wv][n + 0] * FOUT];
    const float v1 = sup[(size_t)nbr[wv][n + 1] * FOUT];
    const float v2 = sup[(size_t)nbr[wv][n + 2] * FOUT];
    const float v3 = sup[(size_t)nbr[wv][n + 3] * FOUT];
    s0 += v0; c0 += (v0 != 0.f);
    s1 += v1; c1 += (v1 != 0.f);
    s2 += v2; c2 += (v2 != 0.f);
    s3 += v3; c3 += (v3 != 0.f);
  }
  for (; n < m; ++n) {
    const float v = sup[(size_t)nbr[wv][n] * FOUT];
    s0 += v; c0 += (v != 0.f);
  }
  sred[wv][lane] = (s0 + s1) + (s2 + s3);
  cred[wv][lane] = (c0 + c1) + (c2 + c3);
  __syncthreads();

  if (t < FOUT) {
    const float s = sred[0][t] + sred[1][t] + sred[2][t] + sred[3][t];
    const int   c = cred[0][t] + cred[1][t] + cred[2][t] + cred[3][t];
    out[(size_t)row * FOUT + t] = s / (float)c + bias[t];
  }
}

extern "C" void kernel_launch(void* const* d_in, const int* in_sizes, int n_in,
                              void* d_out, int out_size, void* d_ws, size_t ws_size,
                              hipStream_t stream) {
  const float* x    = (const float*)d_in[0];
  const float* adj  = (const float*)d_in[1];
  const float* w    = (const float*)d_in[2];
  const float* bias = (const float*)d_in[3];
  float* out = (float*)d_out;
  float* support = (float*)d_ws;   // 4 MB scratch

  support_gemm<<<N_NODES / 16, 256, 0, stream>>>(x, w, support);
  aggregate<<<N_NODES, 256, 0, stream>>>(adj, support, bias, out);
}